// Round 11
// baseline (197.694 us; speedup 1.0000x reference)
//
#include <hip/hip_runtime.h>
#include <hip/hip_bf16.h>

#define SEQ   2048
#define DIM   1024
#define NH    16
#define NKV   4
#define HDIM  64
#define BATCH 2
#define MROWS (BATCH*SEQ)   // 4096
#define NT2   (SEQ/32)      // 64 kv tiles of 32 keys

typedef __attribute__((ext_vector_type(8))) short bf16x8;
typedef __attribute__((ext_vector_type(2))) float f32x2;
typedef __attribute__((ext_vector_type(4))) float f32x4;

static __device__ __forceinline__ short f2bf(float f) {
    unsigned u = __builtin_bit_cast(unsigned, f);
    u += 0x7fffu + ((u >> 16) & 1u);
    return (short)(u >> 16);
}

static __device__ __forceinline__ void gload16(const short* g, short* l) {
    __builtin_amdgcn_global_load_lds((const __attribute__((address_space(1))) void*)g,
                                     (__attribute__((address_space(3))) void*)l, 16, 0, 0);
}

// ---------- prepass: f32 -> bf16 contiguous ----------
__global__ __launch_bounds__(256)
void cvt_bf16(const float* __restrict__ src, short* __restrict__ dst, int n8) {
    int i = blockIdx.x * 256 + threadIdx.x;
    if (i >= n8) return;
    const float* s = src + (size_t)i * 8;
    f32x4 a = *reinterpret_cast<const f32x4*>(s);
    f32x4 b = *reinterpret_cast<const f32x4*>(s + 4);
    bf16x8 o;
    #pragma unroll
    for (int j = 0; j < 4; ++j) { o[j] = f2bf(a[j]); o[j+4] = f2bf(b[j]); }
    *reinterpret_cast<bf16x8*>(dst + (size_t)i * 8) = o;
}

// ---------- prepass: all 4 weights, W[K=1024][N] f32 -> Wt[N][1024] bf16 ----------
__global__ __launch_bounds__(256)
void tconv4(const float* __restrict__ wq, const float* __restrict__ wk,
            const float* __restrict__ wv, const float* __restrict__ wo,
            short* __restrict__ Wt, short* __restrict__ Wto) {
    __shared__ short Ts[64][72];
    const float* src; short* dst; int N;
    if      (blockIdx.z == 0) { src = wq; dst = Wt;               N = 1024; }
    else if (blockIdx.z == 1) { src = wk; dst = Wt + 1024*1024;   N = 256;  }
    else if (blockIdx.z == 2) { src = wv; dst = Wt + 1280*1024;   N = 256;  }
    else                      { src = wo; dst = Wto;              N = 1024; }
    const int n0 = blockIdx.x * 64;
    if (n0 >= N) return;
    const int k0 = blockIdx.y * 64;
    const int t = threadIdx.x;
    {
        int r = t >> 4, cg = (t & 15) * 4;
        #pragma unroll
        for (int j = 0; j < 4; ++j) {
            f32x4 v = *reinterpret_cast<const f32x4*>(&src[(size_t)(k0 + r + j*16) * N + n0 + cg]);
            #pragma unroll
            for (int q = 0; q < 4; ++q) Ts[r + j*16][cg + q] = f2bf(v[q]);
        }
    }
    __syncthreads();
    {
        int rr = t >> 3, cc = (t & 7) * 8;
        #pragma unroll
        for (int j = 0; j < 2; ++j) {
            bf16x8 o;
            #pragma unroll
            for (int q = 0; q < 8; ++q) o[q] = Ts[cc + q][rr + j*32];
            *reinterpret_cast<bf16x8*>(&dst[(size_t)(n0 + rr + j*32) * 1024 + k0 + cc]) = o;
        }
    }
}

// ---------- m97-style GEMM, 128M x 64N tile: A[4096][1024] bf16 × Bt[N][1024] bf16 ----------
template<int MODE>
__global__ __launch_bounds__(256)
void mm97(const short* __restrict__ A, const short* __restrict__ Bt,
          short* __restrict__ q_out, short* __restrict__ k_out, short* __restrict__ v_out,
          float* __restrict__ f_out)
{
    __shared__ short As[128][32];
    __shared__ short Bs[64][32];
    const int m0 = blockIdx.y * 128, n0 = blockIdx.x * 64;
    const int t = threadIdx.x, wv = t >> 6, l = t & 63, lg = l >> 4, li = l & 15;
    const int wr = wv >> 1, wc = wv & 1;
    f32x4 acc[4][2] = {};

    const short* ga = A  + (size_t)(m0 + (t >> 2)) * 1024 + (t & 3) * 8;
    const short* gb = Bt + (size_t)(n0 + (t >> 2)) * 1024 + (t & 3) * 8;
    short* la = (short*)As + t * 8;
    short* lb = (short*)Bs + t * 8;

    for (int k0 = 0; k0 < 1024; k0 += 32) {
        gload16(ga + k0,            la);
        gload16(ga + 64*1024 + k0,  la + 2048);
        gload16(gb + k0,            lb);
        __syncthreads();
        bf16x8 av[4], bv[2];
        #pragma unroll
        for (int m = 0; m < 4; ++m)
            av[m] = *reinterpret_cast<const bf16x8*>(&As[wr*64 + m*16 + li][lg*8]);
        #pragma unroll
        for (int n = 0; n < 2; ++n)
            bv[n] = *reinterpret_cast<const bf16x8*>(&Bs[wc*32 + n*16 + li][lg*8]);
        #pragma unroll
        for (int m = 0; m < 4; ++m)
            #pragma unroll
            for (int n = 0; n < 2; ++n)
                acc[m][n] = __builtin_amdgcn_mfma_f32_16x16x32_bf16(av[m], bv[n], acc[m][n], 0, 0, 0);
        __syncthreads();
    }

    #pragma unroll
    for (int m = 0; m < 4; ++m) {
        #pragma unroll
        for (int n = 0; n < 2; ++n) {
            #pragma unroll
            for (int r = 0; r < 4; ++r) {
                int row = m0 + wr*64 + m*16 + lg*4 + r;
                int col = n0 + wc*32 + n*16 + li;
                float v = acc[m][n][r];
                if constexpr (MODE == 0) {
                    int b = row >> 11, s = row & (SEQ-1);
                    if (col < 1024) {
                        q_out[(((size_t)((b*NH + (col>>6))*SEQ + s)) << 6) + (col & 63)] = f2bf(v);
                    } else if (col < 1280) {
                        int c1 = col - 1024;
                        k_out[(((size_t)((b*NKV + (c1>>6))*SEQ + s)) << 6) + (c1 & 63)] = f2bf(v);
                    } else {
                        int c1 = col - 1280;
                        v_out[((size_t)((b*NKV + (c1>>6))*HDIM + (c1 & 63)))*SEQ + s] = f2bf(v);
                    }
                } else {
                    f_out[(size_t)row * 1024 + col] = v;
                }
            }
        }
    }
}

// ---------- flash attention, high block-parallelism ----------
// grid (S/32, B*NH) = 2048 blocks; block = 128 threads (2 waves x 16 q-rows).
// KVBLK=32, LDS 18.4 KB -> 8 blocks/CU (double R4's independent blocks/CU;
// barrier convoys only 2 waves). K slot-pair-permuted: slot c*16+li holds key
// li*2+c -> lane's 2 score cols contiguous -> pb dwordx2, P-write b32.
// Ks rows 128B swz ((slot&7)<<4); Vs/Ps rows 64B swz ((row&3)<<4).
// Dbuf gload_lds; pb 1 tile ahead; FIFO vmcnt(4) (stage before pb).
__global__ __launch_bounds__(128, 4)
void gqa_attn(const short* __restrict__ Qh, const short* __restrict__ Kh,
              const short* __restrict__ Vt, const float* __restrict__ pb,
              short* __restrict__ AO)
{
    __shared__ short Ks[2][32][64];    // [buf][slot][d]
    __shared__ short Vs[2][64][32];    // [buf][d][key]
    __shared__ short Ps[2][16][32];    // [wave][q][key]
    const int q0 = blockIdx.x * 32;
    const int bh = blockIdx.y, hq = bh >> 1, b = bh & 1, hkv = hq >> 2;
    const int t = threadIdx.x, wv = t >> 6, l = t & 63, lg = l >> 4, li = l & 15;

    const short* Qp = Qh + ((size_t)(b*NH  + hq )*SEQ)*HDIM;
    const short* Kp = Kh + ((size_t)(b*NKV + hkv)*SEQ)*HDIM;
    const short* Vp = Vt + ((size_t)(b*NKV + hkv)*HDIM)*SEQ;

    // K staging: wave wv covers slots wv*16..+16 (2 gloads of 8 slots);
    // slot s holds key (s&15)*2 + (s>>4); chunk pre-swizzled by slot&7 = l>>3.
    const int lr8  = l >> 3;
    const int kbb  = (l & 7) ^ lr8;
    const int slotA = wv*16 + lr8,  slotB = slotA + 8;
    const size_t kOffA = (size_t)((slotA & 15)*2 + (slotA >> 4))*HDIM + kbb*8;
    const size_t kOffB = (size_t)((slotB & 15)*2 + (slotB >> 4))*HDIM + kbb*8;
    // V staging: wave wv covers d-rows wv*32..+32 (2 gloads of 16 rows);
    // 64B rows, chunk pre-swizzled by row&3 = (l>>2)&3.
    const int vbb = (l & 3) ^ ((l >> 2) & 3);
    const size_t vOffA = (size_t)(wv*32 + (l >> 2))*SEQ + vbb*8;
    const size_t vOffB = vOffA + (size_t)16*SEQ;

    bf16x8 qa[2];
    {
        int qr = q0 + wv*16 + li;
        qa[0] = *reinterpret_cast<const bf16x8*>(&Qp[(size_t)qr*HDIM + lg*8]);
        qa[1] = *reinterpret_cast<const bf16x8*>(&Qp[(size_t)qr*HDIM + 32 + lg*8]);
    }
    // pb rows q0+wv*16+lg*4+r, cols li*2, li*2+1 (contiguous via pair-permute)
    const float* pbp = pb + ((size_t)hq*SEQ + q0 + wv*16 + lg*4)*SEQ + li*2;

    char* PsW = (char*)Ps + wv*1024;
    const int swl = (li & 7) << 4;     // K-read swizzle (128B rows)
    const int sw3 = (li & 3) << 4;     // V/P-read swizzle (64B rows)

    f32x4 oacc[4] = {};
    float lrow[4] = {};
    f32x2 pbq[4];

#define STAGE(nxt, kk) do { \
    gload16(Kp + (size_t)(kk)*HDIM + kOffA, &Ks[nxt][wv*16][0]);      \
    gload16(Kp + (size_t)(kk)*HDIM + kOffB, &Ks[nxt][wv*16 + 8][0]);  \
    gload16(Vp + (size_t)(kk) + vOffA,      &Vs[nxt][wv*32][0]);      \
    gload16(Vp + (size_t)(kk) + vOffB,      &Vs[nxt][wv*32 + 16][0]); \
    __builtin_amdgcn_sched_barrier(0); \
} while (0)

#define PBLOAD(kk) do { \
    _Pragma("unroll") \
    for (int r = 0; r < 4; ++r) \
        pbq[r] = *reinterpret_cast<const f32x2*>(pbp + (size_t)r*SEQ + (kk)); \
    __builtin_amdgcn_sched_barrier(0); \
} while (0)

    // prologue: stage tile 0, prefetch pb tile 0
    STAGE(0, 0);
    PBLOAD(0);
    asm volatile("s_waitcnt vmcnt(4)" ::: "memory");   // stage done, pb in flight
    __builtin_amdgcn_s_barrier();

    #pragma unroll 1
    for (int kt = 0; kt < NT2; ++kt) {
        const int cur = kt & 1;
        const char* kbase = (const char*)&Ks[cur][0][0];
        const char* vbase = (const char*)&Vs[cur][0][0];

        if (kt < NT2 - 1) STAGE(cur ^ 1, (kt + 1)*32);

        // QK^T: 16q × 32key; fragment c = keys li*2+c (pair-permuted slots)
        f32x4 sacc[2] = {};
        __builtin_amdgcn_s_setprio(1);
        #pragma unroll
        for (int c = 0; c < 2; ++c) {
            const char* kb = kbase + (c*16 + li)*128;
            bf16x8 kv0 = *(const bf16x8*)(kb + ((     lg*16) ^ swl));
            bf16x8 kv1 = *(const bf16x8*)(kb + ((64 + lg*16) ^ swl));
            sacc[c] = __builtin_amdgcn_mfma_f32_16x16x32_bf16(qa[0], kv0, sacc[c], 0, 0, 0);
            sacc[c] = __builtin_amdgcn_mfma_f32_16x16x32_bf16(qa[1], kv1, sacc[c], 0, 0, 0);
        }
        __builtin_amdgcn_s_setprio(0);

        // fixed-max softmax: p = exp2(qk/8*L2E + pb*L2E - 12*L2E); sum deferred
        #pragma unroll
        for (int r = 0; r < 4; ++r) {
            float p0 = exp2f(fmaf(sacc[0][r], 0.1803368801f,
                             fmaf(pbq[r].x, 1.442695041f, -17.31234049f)));
            float p1 = exp2f(fmaf(sacc[1][r], 0.1803368801f,
                             fmaf(pbq[r].y, 1.442695041f, -17.31234049f)));
            lrow[r] += p0 + p1;
            unsigned pk = (unsigned)(unsigned short)f2bf(p0)
                        | ((unsigned)(unsigned short)f2bf(p1) << 16);
            *(unsigned*)(PsW + (lg*4 + r)*64 + ((li*4) ^ (r << 4))) = pk;
        }

        if (kt < NT2 - 1) PBLOAD((kt + 1)*32);

        // PV: oacc[c2] += P[16q x 32k] * V^T[64d x 32k]
        __builtin_amdgcn_s_setprio(1);
        bf16x8 pa = *(const bf16x8*)(PsW + li*64 + ((lg*16) ^ sw3));
        #pragma unroll
        for (int c2 = 0; c2 < 4; ++c2) {
            bf16x8 vb = *(const bf16x8*)(vbase + (c2*16 + li)*64 + ((lg*16) ^ sw3));
            oacc[c2] = __builtin_amdgcn_mfma_f32_16x16x32_bf16(pa, vb, oacc[c2], 0, 0, 0);
        }
        __builtin_amdgcn_s_setprio(0);

        __builtin_amdgcn_sched_barrier(0);
        // FIFO outstanding: [stage 4 (older)][pb 4 (newer)] -> drain stage only
        if (kt < NT2 - 1) asm volatile("s_waitcnt vmcnt(4)" ::: "memory");
        else              asm volatile("s_waitcnt vmcnt(0)" ::: "memory");
        __builtin_amdgcn_s_barrier();
    }
#undef STAGE
#undef PBLOAD

    // epilogue: reduce row-sums across the 16 lanes holding each row, store AO
    #pragma unroll
    for (int r = 0; r < 4; ++r) {
        float s = lrow[r];
        s += __shfl_xor(s, 1); s += __shfl_xor(s, 2);
        s += __shfl_xor(s, 4); s += __shfl_xor(s, 8);
        float inv = 1.0f / s;
        int qrow = q0 + wv*16 + lg*4 + r;
        short* ao = AO + (((size_t)(b*SEQ + qrow)) << 10) + hq*HDIM;
        #pragma unroll
        for (int c2 = 0; c2 < 4; ++c2)
            ao[c2*16 + li] = f2bf(oacc[c2][r] * inv);
    }
}

extern "C" void kernel_launch(void* const* d_in, const int* in_sizes, int n_in,
                              void* d_out, int out_size, void* d_ws, size_t ws_size,
                              hipStream_t stream)
{
    const float* x    = (const float*)d_in[0];
    const float* wq   = (const float*)d_in[1];
    const float* wk   = (const float*)d_in[2];
    const float* wvp  = (const float*)d_in[3];
    const float* wo   = (const float*)d_in[4];
    const float* pb   = (const float*)d_in[5];

    char* ws = (char*)d_ws;
    short* Xb  = (short*)(ws);                      // [4096][1024] bf16, 8 MB
    short* AO  = (short*)(ws);                      // aliases Xb (Xb dead before attn writes AO)
    short* Wt  = (short*)(ws + 8388608);            // [1536][1024] bf16, 3 MB (Q|K|V transposed)
    short* Wto = (short*)(ws + 11534336);           // [1024][1024] bf16, 2 MB
    short* Qh  = (short*)(ws + 13631488);           // [B,NH,S,64]  bf16, 8 MB
    short* Kh  = (short*)(ws + 22020096);           // [B,NKV,S,64] bf16, 2 MB
    short* Vt  = (short*)(ws + 24117248);           // [B,NKV,64,S] bf16, 2 MB

    dim3 blk(256);
    cvt_bf16<<<dim3(MROWS*DIM/8/256), blk, 0, stream>>>(x, Xb, MROWS*DIM/8);
    tconv4<<<dim3(16, 16, 4), blk, 0, stream>>>(wq, wk, wvp, wo, Wt, Wto);
    mm97<0><<<dim3(24, 32), blk, 0, stream>>>(Xb, Wt,  Qh, Kh, Vt, nullptr);
    gqa_attn<<<dim3(SEQ/32, BATCH*NH), dim3(128), 0, stream>>>(Qh, Kh, Vt, pb, AO);
    mm97<1><<<dim3(16, 32), blk, 0, stream>>>(AO, Wto, nullptr, nullptr, nullptr, (float*)d_out);
}

// Round 12
// 159.072 us; speedup vs baseline: 1.2428x; 1.2428x over previous
//
#include <hip/hip_runtime.h>
#include <hip/hip_bf16.h>

#define SEQ   2048
#define DIM   1024
#define NH    16
#define NKV   4
#define HDIM  64
#define BATCH 2
#define MROWS (BATCH*SEQ)   // 4096
#define NSPLIT 2
#define NTS   (SEQ/NSPLIT/64)   // 16 kv tiles per split

typedef __attribute__((ext_vector_type(8))) short bf16x8;
typedef __attribute__((ext_vector_type(4))) short shortx4;
typedef __attribute__((ext_vector_type(4))) float f32x4;

static __device__ __forceinline__ short f2bf(float f) {
    unsigned u = __builtin_bit_cast(unsigned, f);
    u += 0x7fffu + ((u >> 16) & 1u);
    return (short)(u >> 16);
}
static __device__ __forceinline__ float bf2f(short s) {
    unsigned u = ((unsigned)(unsigned short)s) << 16;
    return __builtin_bit_cast(float, u);
}

static __device__ __forceinline__ void gload16(const short* g, short* l) {
    __builtin_amdgcn_global_load_lds((const __attribute__((address_space(1))) void*)g,
                                     (__attribute__((address_space(3))) void*)l, 16, 0, 0);
}

// ---------- prepass: f32 -> bf16 contiguous ----------
__global__ __launch_bounds__(256)
void cvt_bf16(const float* __restrict__ src, short* __restrict__ dst, int n8) {
    int i = blockIdx.x * 256 + threadIdx.x;
    if (i >= n8) return;
    const float* s = src + (size_t)i * 8;
    f32x4 a = *reinterpret_cast<const f32x4*>(s);
    f32x4 b = *reinterpret_cast<const f32x4*>(s + 4);
    bf16x8 o;
    #pragma unroll
    for (int j = 0; j < 4; ++j) { o[j] = f2bf(a[j]); o[j+4] = f2bf(b[j]); }
    *reinterpret_cast<bf16x8*>(dst + (size_t)i * 8) = o;
}

// ---------- prepass: all 4 weights, W[K=1024][N] f32 -> Wt[N][1024] bf16 ----------
__global__ __launch_bounds__(256)
void tconv4(const float* __restrict__ wq, const float* __restrict__ wk,
            const float* __restrict__ wv, const float* __restrict__ wo,
            short* __restrict__ Wt, short* __restrict__ Wto) {
    __shared__ short Ts[64][72];
    const float* src; short* dst; int N;
    if      (blockIdx.z == 0) { src = wq; dst = Wt;               N = 1024; }
    else if (blockIdx.z == 1) { src = wk; dst = Wt + 1024*1024;   N = 256;  }
    else if (blockIdx.z == 2) { src = wv; dst = Wt + 1280*1024;   N = 256;  }
    else                      { src = wo; dst = Wto;              N = 1024; }
    const int n0 = blockIdx.x * 64;
    if (n0 >= N) return;
    const int k0 = blockIdx.y * 64;
    const int t = threadIdx.x;
    {
        int r = t >> 4, cg = (t & 15) * 4;
        #pragma unroll
        for (int j = 0; j < 4; ++j) {
            f32x4 v = *reinterpret_cast<const f32x4*>(&src[(size_t)(k0 + r + j*16) * N + n0 + cg]);
            #pragma unroll
            for (int q = 0; q < 4; ++q) Ts[r + j*16][cg + q] = f2bf(v[q]);
        }
    }
    __syncthreads();
    {
        int rr = t >> 3, cc = (t & 7) * 8;
        #pragma unroll
        for (int j = 0; j < 2; ++j) {
            bf16x8 o;
            #pragma unroll
            for (int q = 0; q < 8; ++q) o[q] = Ts[cc + q][rr + j*32];
            *reinterpret_cast<bf16x8*>(&dst[(size_t)(n0 + rr + j*32) * 1024 + k0 + cc]) = o;
        }
    }
}

// ---------- m97-style GEMM, 128M x 64N tile: A[4096][1024] bf16 × Bt[N][1024] bf16 ----------
template<int MODE>
__global__ __launch_bounds__(256)
void mm97(const short* __restrict__ A, const short* __restrict__ Bt,
          short* __restrict__ q_out, short* __restrict__ k_out, short* __restrict__ v_out,
          float* __restrict__ f_out)
{
    __shared__ short As[128][32];
    __shared__ short Bs[64][32];
    const int m0 = blockIdx.y * 128, n0 = blockIdx.x * 64;
    const int t = threadIdx.x, wv = t >> 6, l = t & 63, lg = l >> 4, li = l & 15;
    const int wr = wv >> 1, wc = wv & 1;
    f32x4 acc[4][2] = {};

    const short* ga = A  + (size_t)(m0 + (t >> 2)) * 1024 + (t & 3) * 8;
    const short* gb = Bt + (size_t)(n0 + (t >> 2)) * 1024 + (t & 3) * 8;
    short* la = (short*)As + t * 8;
    short* lb = (short*)Bs + t * 8;

    for (int k0 = 0; k0 < 1024; k0 += 32) {
        gload16(ga + k0,            la);
        gload16(ga + 64*1024 + k0,  la + 2048);
        gload16(gb + k0,            lb);
        __syncthreads();
        bf16x8 av[4], bv[2];
        #pragma unroll
        for (int m = 0; m < 4; ++m)
            av[m] = *reinterpret_cast<const bf16x8*>(&As[wr*64 + m*16 + li][lg*8]);
        #pragma unroll
        for (int n = 0; n < 2; ++n)
            bv[n] = *reinterpret_cast<const bf16x8*>(&Bs[wc*32 + n*16 + li][lg*8]);
        #pragma unroll
        for (int m = 0; m < 4; ++m)
            #pragma unroll
            for (int n = 0; n < 2; ++n)
                acc[m][n] = __builtin_amdgcn_mfma_f32_16x16x32_bf16(av[m], bv[n], acc[m][n], 0, 0, 0);
        __syncthreads();
    }

    #pragma unroll
    for (int m = 0; m < 4; ++m) {
        #pragma unroll
        for (int n = 0; n < 2; ++n) {
            #pragma unroll
            for (int r = 0; r < 4; ++r) {
                int row = m0 + wr*64 + m*16 + lg*4 + r;
                int col = n0 + wc*32 + n*16 + li;
                float v = acc[m][n][r];
                if constexpr (MODE == 0) {
                    int b = row >> 11, s = row & (SEQ-1);
                    if (col < 1024) {
                        q_out[(((size_t)((b*NH + (col>>6))*SEQ + s)) << 6) + (col & 63)] = f2bf(v);
                    } else if (col < 1280) {
                        int c1 = col - 1024;
                        k_out[(((size_t)((b*NKV + (c1>>6))*SEQ + s)) << 6) + (c1 & 63)] = f2bf(v);
                    } else {
                        int c1 = col - 1280;
                        v_out[((size_t)((b*NKV + (c1>>6))*HDIM + (c1 & 63)))*SEQ + s] = f2bf(v);
                    }
                } else {
                    f_out[(size_t)row * 1024 + col] = v;
                }
            }
        }
    }
}

// ---------- flash attention, split-K: grid (S/64, B*NH, NSPLIT) ----------
// blockIdx.z = kv-half; each block does NT=16 tile-iterations over keys
// [z*1024, +1024). Fixed-max softmax (exp(s-12)) makes splits independent:
// combine = sum(oacc)/sum(lrow) in sm_reduce. R4 structure otherwise:
// 4 waves x 16 q-rows, gload_lds dbuf K/V, key-permuted K slots, pb->regs
// 1 tile ahead, FIFO vmcnt(4) (stage issued before pb). Unnormalized bf16
// partials + f32 row-sums to workspace.
__global__ __launch_bounds__(256, 4)
void gqa_attn(const short* __restrict__ Qh, const short* __restrict__ Kh,
              const short* __restrict__ Vt, const float* __restrict__ pb,
              short* __restrict__ Op, float* __restrict__ Lp)
{
    __shared__ short Ks[2][64][64];    // [buf][slot][d], swizzled, slot-permuted
    __shared__ short Vs[2][64][64];    // [buf][d][key],  swizzled, natural
    __shared__ short Ps[4][16][64];    // per-wave P [q][key], swizzled
    const int q0 = blockIdx.x * 64;
    const int bh = blockIdx.y, hq = bh >> 1, b = bh & 1, hkv = hq >> 2;
    const int kh = blockIdx.z;             // kv half
    const int kbase0 = kh * (SEQ/NSPLIT);  // first key of this split
    const int t = threadIdx.x, wv = t >> 6, l = t & 63, lg = l >> 4, li = l & 15;
    const int swl = (li & 7) << 4;

    const short* Qp = Qh + ((size_t)(b*NH  + hq )*SEQ)*HDIM;
    const short* Kp = Kh + ((size_t)(b*NKV + hkv)*SEQ)*HDIM + (size_t)kbase0*HDIM;
    const short* Vp = Vt + ((size_t)(b*NKV + hkv)*HDIM)*SEQ + kbase0;

    // staging: lane l covers slot (wv*16 + l>>3) [+8], 16B chunk (l&7)^(l>>3)
    const int lr8 = l >> 3;
    const int bb  = (l & 7) ^ lr8;
    const int kOff0 = (lr8*4 + wv)*HDIM + bb*8;     // slot wv*16+lr8 holds key lr8*4+wv
    const int kOff1 = kOff0 + 32*HDIM;              // slot +8 holds key +32
    const size_t vOff0 = (size_t)(wv*16 + lr8)*SEQ + bb*8;
    const size_t vOff1 = vOff0 + (size_t)8*SEQ;

    bf16x8 qa[2];
    {
        int qr = q0 + wv*16 + li;
        qa[0] = *reinterpret_cast<const bf16x8*>(&Qp[(size_t)qr*HDIM + lg*8]);
        qa[1] = *reinterpret_cast<const bf16x8*>(&Qp[(size_t)qr*HDIM + 32 + lg*8]);
    }

    // pb rows q0+wv*16+lg*4+r, cols kbase0 + li*4.. (contiguous via key-permute)
    const float* pbp = pb + ((size_t)hq*SEQ + q0 + wv*16 + lg*4)*SEQ + kbase0 + li*4;

    f32x4 oacc[4] = {};
    float lrow[4] = {};
    f32x4 pbq[4];
    char* PsW = (char*)Ps + wv*2048;

#define STAGE(nxt, kk) do { \
    gload16(Kp + (size_t)(kk)*HDIM + kOff0, &Ks[nxt][wv*16][0]);     \
    gload16(Kp + (size_t)(kk)*HDIM + kOff1, &Ks[nxt][wv*16 + 8][0]); \
    gload16(Vp + (size_t)(kk) + vOff0,      &Vs[nxt][wv*16][0]);     \
    gload16(Vp + (size_t)(kk) + vOff1,      &Vs[nxt][wv*16 + 8][0]); \
} while (0)

#define PBLOAD(kk) do { \
    _Pragma("unroll") \
    for (int r = 0; r < 4; ++r) \
        pbq[r] = *reinterpret_cast<const f32x4*>(pbp + (size_t)r*SEQ + (kk)); \
} while (0)

    // prologue: tile 0
    STAGE(0, 0);
    PBLOAD(0);
    asm volatile("s_waitcnt vmcnt(0)" ::: "memory");
    __builtin_amdgcn_s_barrier();

    #pragma unroll 1
    for (int kt = 0; kt < NTS; ++kt) {
        const int cur = kt & 1;
        const char* kb0 = (const char*)&Ks[cur][0][0];
        const char* vbase = (const char*)&Vs[cur][0][0];

        if (kt < NTS - 1) {
            STAGE(cur ^ 1, (kt + 1)*64);
            __builtin_amdgcn_sched_barrier(0);
        }

        // QK^T: fragment c = keys li*4+c (permuted slots)
        f32x4 sacc[4] = {};
        __builtin_amdgcn_s_setprio(1);
        #pragma unroll
        for (int c = 0; c < 4; ++c) {
            const char* kb = kb0 + (c*16 + li)*128;
            bf16x8 kv0 = *(const bf16x8*)(kb + ((     lg*16) ^ swl));
            bf16x8 kv1 = *(const bf16x8*)(kb + ((64 + lg*16) ^ swl));
            sacc[c] = __builtin_amdgcn_mfma_f32_16x16x32_bf16(qa[0], kv0, sacc[c], 0, 0, 0);
            sacc[c] = __builtin_amdgcn_mfma_f32_16x16x32_bf16(qa[1], kv1, sacc[c], 0, 0, 0);
        }
        __builtin_amdgcn_s_setprio(0);

        // fixed-max softmax: p = exp(s - 12); packed b64 P write at natural keys
        #pragma unroll
        for (int r = 0; r < 4; ++r) {
            char* pw = PsW + (lg*4 + r)*128;
            const int swp = ((lg*4 + r) & 7) << 4;
            float rs = 0.f;
            shortx4 pk;
            #pragma unroll
            for (int c = 0; c < 4; ++c) {
                float s_ = fmaf(sacc[c][r], 0.125f, pbq[r][c]);
                float p  = __expf(s_ - 12.0f);
                rs += p;
                pk[c] = f2bf(p);
            }
            *(shortx4*)(pw + ((li*8) ^ swp)) = pk;
            lrow[r] += rs;
        }

        if (kt < NTS - 1) {
            PBLOAD((kt + 1)*64);
            __builtin_amdgcn_sched_barrier(0);
        }

        // PV: oacc[c2] += P[16x64] * V^T[64d x 64key]
        __builtin_amdgcn_s_setprio(1);
        #pragma unroll
        for (int h = 0; h < 2; ++h) {
            bf16x8 pa = *(const bf16x8*)(PsW + li*128 + ((h*64 + lg*16) ^ swl));
            #pragma unroll
            for (int c2 = 0; c2 < 4; ++c2) {
                bf16x8 vb = *(const bf16x8*)(vbase + (c2*16 + li)*128 + ((h*64 + lg*16) ^ swl));
                oacc[c2] = __builtin_amdgcn_mfma_f32_16x16x32_bf16(pa, vb, oacc[c2], 0, 0, 0);
            }
        }
        __builtin_amdgcn_s_setprio(0);

        __builtin_amdgcn_sched_barrier(0);
        // FIFO outstanding: [stage 4 (older)][pb 4 (newer)] -> drain stage only
        if (kt < NTS - 1) asm volatile("s_waitcnt vmcnt(4)" ::: "memory");
        else              asm volatile("s_waitcnt vmcnt(0)" ::: "memory");
        __builtin_amdgcn_s_barrier();
    }
#undef STAGE
#undef PBLOAD

    // epilogue: UNNORMALIZED partials. Row-sum reduced across 16 lanes; lane 0
    // writes Lp; all lanes write bf16 oacc partial.
    #pragma unroll
    for (int r = 0; r < 4; ++r) {
        float s = lrow[r];
        s += __shfl_xor(s, 1); s += __shfl_xor(s, 2);
        s += __shfl_xor(s, 4); s += __shfl_xor(s, 8);
        int qrow = q0 + wv*16 + lg*4 + r;
        int row  = b*SEQ + qrow;
        if (li == 0) Lp[(size_t)kh*MROWS*NH + (size_t)row*NH + hq] = s;
        short* op = Op + ((size_t)kh*MROWS + row)*1024 + hq*HDIM;
        #pragma unroll
        for (int c2 = 0; c2 < 4; ++c2)
            op[c2*16 + li] = f2bf(oacc[c2][r]);
    }
}

// ---------- combine split-K partials: AO = (sum Op_i) / (sum L_i), bf16 ----------
__global__ __launch_bounds__(256)
void sm_reduce(const short* __restrict__ Op, const float* __restrict__ Lp,
               short* __restrict__ AO)
{
    int i = blockIdx.x * 256 + threadIdx.x;       // 524288 threads, 8 cols each
    int row = i >> 7;
    int cg  = (i & 127) * 8;
    int hq  = cg >> 6;
    float l = Lp[(size_t)row*NH + hq] + Lp[(size_t)MROWS*NH + (size_t)row*NH + hq];
    float inv = 1.0f / l;
    bf16x8 a = *reinterpret_cast<const bf16x8*>(Op + (size_t)row*1024 + cg);
    bf16x8 b = *reinterpret_cast<const bf16x8*>(Op + ((size_t)MROWS + row)*1024 + cg);
    bf16x8 o;
    #pragma unroll
    for (int j = 0; j < 8; ++j)
        o[j] = f2bf((bf2f(a[j]) + bf2f(b[j])) * inv);
    *reinterpret_cast<bf16x8*>(AO + (size_t)row*1024 + cg) = o;
}

extern "C" void kernel_launch(void* const* d_in, const int* in_sizes, int n_in,
                              void* d_out, int out_size, void* d_ws, size_t ws_size,
                              hipStream_t stream)
{
    const float* x    = (const float*)d_in[0];
    const float* wq   = (const float*)d_in[1];
    const float* wk   = (const float*)d_in[2];
    const float* wvp  = (const float*)d_in[3];
    const float* wo   = (const float*)d_in[4];
    const float* pb   = (const float*)d_in[5];

    char* ws = (char*)d_ws;
    short* Xb  = (short*)(ws);                      // [4096][1024] bf16, 8 MB
    short* AO  = (short*)(ws);                      // aliases Xb (dead before reduce)
    short* Wt  = (short*)(ws + 8388608);            // [1536][1024] bf16, 3 MB
    short* Wto = (short*)(ws + 11534336);           // [1024][1024] bf16, 2 MB
    short* Qh  = (short*)(ws + 13631488);           // [B,NH,S,64]  bf16, 8 MB
    short* Kh  = (short*)(ws + 22020096);           // [B,NKV,S,64] bf16, 2 MB
    short* Vt  = (short*)(ws + 24117248);           // [B,NKV,64,S] bf16, 2 MB
    short* Op  = (short*)(ws + 26214400);           // [2][4096][1024] bf16, 16 MB
    float* Lp  = (float*)(ws + 42991616);           // [2][4096][16] f32, 0.5 MB

    dim3 blk(256);
    cvt_bf16<<<dim3(MROWS*DIM/8/256), blk, 0, stream>>>(x, Xb, MROWS*DIM/8);
    tconv4<<<dim3(16, 16, 4), blk, 0, stream>>>(wq, wk, wvp, wo, Wt, Wto);
    mm97<0><<<dim3(24, 32), blk, 0, stream>>>(Xb, Wt,  Qh, Kh, Vt, nullptr);
    gqa_attn<<<dim3(SEQ/64, BATCH*NH, NSPLIT), blk, 0, stream>>>(Qh, Kh, Vt, pb, Op, Lp);
    sm_reduce<<<dim3(MROWS*DIM/8/256), blk, 0, stream>>>(Op, Lp, AO);
    mm97<1><<<dim3(16, 32), blk, 0, stream>>>(AO, Wto, nullptr, nullptr, nullptr, (float*)d_out);
}